// Round 1
// baseline (624.313 us; speedup 1.0000x reference)
//
#include <hip/hip_runtime.h>
#include <hip/hip_bf16.h>
#include <math.h>

#define N_NODES 50000
#define N_EDGES 600000
#define NFEAT   256
#define NHID    128
#define NCLASS  40

// ---------------------------------------------------------------------------
// CSR build: histogram of edge_dst
__global__ __launch_bounds__(256) void hist_kernel(const int* __restrict__ dst,
                                                   int* __restrict__ cnt, int E) {
    int i = blockIdx.x * 256 + threadIdx.x;
    if (i < E) atomicAdd(&cnt[dst[i]], 1);
}

// Single-block exclusive scan over n counts -> row_start[n+1], cursor[n]
__global__ __launch_bounds__(1024) void scan_kernel(const int* __restrict__ cnt,
                                                    int* __restrict__ rs,
                                                    int* __restrict__ cur, int n) {
    __shared__ int buf[1024];
    int tid = threadIdx.x;
    int chunk = (n + 1023) / 1024;
    int start = tid * chunk;
    int end = start + chunk; if (end > n) end = n;
    int sum = 0;
    for (int i = start; i < end; ++i) sum += cnt[i];
    buf[tid] = sum;
    __syncthreads();
    // Hillis-Steele inclusive scan
    for (int off = 1; off < 1024; off <<= 1) {
        int t = (tid >= off) ? buf[tid - off] : 0;
        __syncthreads();
        buf[tid] += t;
        __syncthreads();
    }
    int run = buf[tid] - sum;  // exclusive prefix
    for (int i = start; i < end; ++i) {
        rs[i] = run; cur[i] = run;
        run += cnt[i];
    }
    if (tid == 1023) rs[n] = buf[1023];
}

// Scatter edges into dst-sorted order
__global__ __launch_bounds__(256) void scatter_kernel(const int* __restrict__ src,
                                                      const int* __restrict__ dst,
                                                      const float* __restrict__ w,
                                                      int* __restrict__ cur,
                                                      int* __restrict__ ssrc,
                                                      float* __restrict__ sw, int E) {
    int i = blockIdx.x * 256 + threadIdx.x;
    if (i >= E) return;
    int p = atomicAdd(&cur[dst[i]], 1);
    ssrc[p] = src[i];
    sw[p] = w[i];
}

// ---------------------------------------------------------------------------
// C[M,128] = A[M,K] @ B[K,128]; 64x128 tile per block, 256 threads, BK=16
__global__ __launch_bounds__(256) void gemm_n128(const float* __restrict__ A,
                                                 const float* __restrict__ B,
                                                 float* __restrict__ C, int M, int K) {
    __shared__ float a_s[64][16];
    __shared__ float b_s[16][128];
    int tid = threadIdx.x;
    int row0 = blockIdx.x * 64;
    int tx = tid & 31;   // col group: cols tx*4..tx*4+3
    int ty = tid >> 5;   // row group: rows ty*8..ty*8+7
    float acc[8][4] = {};
    for (int k0 = 0; k0 < K; k0 += 16) {
        // A tile: 64 x 16 = 256 float4, one per thread (contiguous LDS write)
        {
            int r = tid >> 2;
            int kc = (tid & 3) << 2;
            int gr = row0 + r;
            float4 v = make_float4(0.f, 0.f, 0.f, 0.f);
            if (gr < M) v = *(const float4*)&A[(size_t)gr * K + k0 + kc];
            *(float4*)&a_s[r][kc] = v;
        }
        // B tile: 16 x 128 = 512 float4, two per thread
        #pragma unroll
        for (int i = 0; i < 2; ++i) {
            int f4 = tid * 2 + i;
            int kr = f4 >> 5;
            int c = (f4 & 31) << 2;
            *(float4*)&b_s[kr][c] = *(const float4*)&B[(size_t)(k0 + kr) * 128 + c];
        }
        __syncthreads();
        #pragma unroll
        for (int k = 0; k < 16; ++k) {
            float4 b4 = *(const float4*)&b_s[k][tx * 4];
            #pragma unroll
            for (int i = 0; i < 8; ++i) {
                float a = a_s[ty * 8 + i][k];
                acc[i][0] += a * b4.x;
                acc[i][1] += a * b4.y;
                acc[i][2] += a * b4.z;
                acc[i][3] += a * b4.w;
            }
        }
        __syncthreads();
    }
    for (int i = 0; i < 8; ++i) {
        int gr = row0 + ty * 8 + i;
        if (gr < M)
            *(float4*)&C[(size_t)gr * 128 + tx * 4] =
                make_float4(acc[i][0], acc[i][1], acc[i][2], acc[i][3]);
    }
}

// C[M,40] = A[M,128] @ W[128,40]  (W is 20KB -> L1-resident)
__global__ __launch_bounds__(256) void gemm_n40(const float* __restrict__ A,
                                                const float* __restrict__ W,
                                                float* __restrict__ C, int M) {
    int idx = blockIdx.x * 256 + threadIdx.x;
    int row = idx / 40;
    int col = idx - row * 40;
    if (row >= M) return;
    const float* a = A + (size_t)row * 128;
    float acc = 0.f;
    #pragma unroll 8
    for (int k = 0; k < 128; ++k) acc += a[k] * W[k * 40 + col];
    C[(size_t)row * 40 + col] = acc;
}

// ---------------------------------------------------------------------------
// out[n,128] = segment_sum over CSR of sup[src]*w + bias, optional relu.
// One wave per node; lane covers 2 features (float2).
__global__ __launch_bounds__(256) void spmm128(const float2* __restrict__ sup,
                                               const int* __restrict__ rs,
                                               const int* __restrict__ ssrc,
                                               const float* __restrict__ sw,
                                               const float* __restrict__ bias,
                                               float2* __restrict__ out, int n,
                                               int do_relu) {
    int wid = blockIdx.x * 4 + (threadIdx.x >> 6);
    int lane = threadIdx.x & 63;
    if (wid >= n) return;
    int k = rs[wid], e = rs[wid + 1];
    float2 acc = make_float2(0.f, 0.f);
    for (; k < e; ++k) {
        int s = ssrc[k];
        float w = sw[k];
        float2 v = sup[(size_t)s * 64 + lane];
        acc.x += v.x * w;
        acc.y += v.y * w;
    }
    float ox = acc.x + bias[lane * 2];
    float oy = acc.y + bias[lane * 2 + 1];
    if (do_relu) { ox = fmaxf(ox, 0.f); oy = fmaxf(oy, 0.f); }
    out[(size_t)wid * 64 + lane] = make_float2(ox, oy);
}

// Same but F=40 (layer 3), writes directly to d_out
__global__ __launch_bounds__(256) void spmm40(const float* __restrict__ sup,
                                              const int* __restrict__ rs,
                                              const int* __restrict__ ssrc,
                                              const float* __restrict__ sw,
                                              const float* __restrict__ bias,
                                              float* __restrict__ out, int n) {
    int wid = blockIdx.x * 4 + (threadIdx.x >> 6);
    int lane = threadIdx.x & 63;
    if (wid >= n) return;
    if (lane < 40) {
        int k = rs[wid], e = rs[wid + 1];
        float acc = 0.f;
        for (; k < e; ++k) acc += sup[(size_t)ssrc[k] * 40 + lane] * sw[k];
        out[(size_t)wid * 40 + lane] = acc + bias[lane];
    }
}

// In-place log_softmax over rows of 40; one wave per row
__global__ __launch_bounds__(256) void logsoftmax40(float* __restrict__ io, int n) {
    int wid = blockIdx.x * 4 + (threadIdx.x >> 6);
    int lane = threadIdx.x & 63;
    if (wid >= n) return;
    float v = (lane < 40) ? io[(size_t)wid * 40 + lane] : -INFINITY;
    float m = v;
    #pragma unroll
    for (int off = 32; off; off >>= 1) m = fmaxf(m, __shfl_xor(m, off, 64));
    float ex = (lane < 40) ? expf(v - m) : 0.f;
    float s = ex;
    #pragma unroll
    for (int off = 32; off; off >>= 1) s += __shfl_xor(s, off, 64);
    float ls = logf(s);
    if (lane < 40) io[(size_t)wid * 40 + lane] = v - m - ls;
}

// ---------------------------------------------------------------------------
extern "C" void kernel_launch(void* const* d_in, const int* in_sizes, int n_in,
                              void* d_out, int out_size, void* d_ws, size_t ws_size,
                              hipStream_t stream) {
    const float* x   = (const float*)d_in[0];
    const float* ew  = (const float*)d_in[1];
    const float* W1  = (const float*)d_in[2];
    const float* b1  = (const float*)d_in[3];
    const float* W2  = (const float*)d_in[4];
    const float* b2  = (const float*)d_in[5];
    const float* W3  = (const float*)d_in[6];
    const float* b3  = (const float*)d_in[7];
    const int* esrc  = (const int*)d_in[8];
    const int* edst  = (const int*)d_in[9];
    float* out = (float*)d_out;

    char* ws = (char*)d_ws;
    size_t off = 0;
    auto alloc = [&](size_t bytes) {
        size_t cur = off;
        off += (bytes + 255) & ~(size_t)255;
        return cur;
    };
    int* cnt      = (int*)(ws + alloc((N_NODES + 1) * sizeof(int)));
    int* rs       = (int*)(ws + alloc((N_NODES + 1) * sizeof(int)));
    int* cur      = (int*)(ws + alloc(N_NODES * sizeof(int)));
    int* ssrc     = (int*)(ws + alloc(N_EDGES * sizeof(int)));
    float* sw     = (float*)(ws + alloc(N_EDGES * sizeof(float)));
    float* bufA   = (float*)(ws + alloc((size_t)N_NODES * 128 * sizeof(float)));
    float* bufB   = (float*)(ws + alloc((size_t)N_NODES * 128 * sizeof(float)));

    // --- CSR build ---
    hipMemsetAsync(cnt, 0, (N_NODES + 1) * sizeof(int), stream);
    hist_kernel<<<(N_EDGES + 255) / 256, 256, 0, stream>>>(edst, cnt, N_EDGES);
    scan_kernel<<<1, 1024, 0, stream>>>(cnt, rs, cur, N_NODES);
    scatter_kernel<<<(N_EDGES + 255) / 256, 256, 0, stream>>>(esrc, edst, ew, cur,
                                                              ssrc, sw, N_EDGES);

    int gemm_blocks = (N_NODES + 63) / 64;           // 782
    int spmm_blocks = (N_NODES + 3) / 4;             // 12500

    // --- layer 1 ---
    gemm_n128<<<gemm_blocks, 256, 0, stream>>>(x, W1, bufA, N_NODES, NFEAT);
    spmm128<<<spmm_blocks, 256, 0, stream>>>((const float2*)bufA, rs, ssrc, sw, b1,
                                             (float2*)bufB, N_NODES, 1);
    // --- layer 2 ---
    gemm_n128<<<gemm_blocks, 256, 0, stream>>>(bufB, W2, bufA, N_NODES, NHID);
    spmm128<<<spmm_blocks, 256, 0, stream>>>((const float2*)bufA, rs, ssrc, sw, b2,
                                             (float2*)bufB, N_NODES, 1);
    // --- layer 3 ---
    gemm_n40<<<((size_t)N_NODES * 40 + 255) / 256, 256, 0, stream>>>(bufB, W3, bufA,
                                                                     N_NODES);
    spmm40<<<spmm_blocks, 256, 0, stream>>>(bufA, rs, ssrc, sw, b3, out, N_NODES);
    logsoftmax40<<<spmm_blocks, 256, 0, stream>>>(out, N_NODES);
}

// Round 2
// 518.867 us; speedup vs baseline: 1.2032x; 1.2032x over previous
//
#include <hip/hip_runtime.h>
#include <hip/hip_bf16.h>
#include <math.h>

#define N_NODES 50000
#define N_EDGES 600000
#define NFEAT   256
#define NHID    128
#define NCLASS  40

// ---------------------------------------------------------------------------
// CSR build: histogram of edge_dst
__global__ __launch_bounds__(256) void hist_kernel(const int* __restrict__ dst,
                                                   int* __restrict__ cnt, int E) {
    int i = blockIdx.x * 256 + threadIdx.x;
    if (i < E) atomicAdd(&cnt[dst[i]], 1);
}

// Device-wide exclusive scan, 3 kernels.
// A: per-block sums (256 elems/block)
__global__ __launch_bounds__(256) void scan_bsum(const int* __restrict__ cnt,
                                                 int* __restrict__ bsum, int n) {
    __shared__ int red[4];
    int i = blockIdx.x * 256 + threadIdx.x;
    int v = (i < n) ? cnt[i] : 0;
    #pragma unroll
    for (int off = 32; off; off >>= 1) v += __shfl_down(v, off, 64);
    int wave = threadIdx.x >> 6, lane = threadIdx.x & 63;
    if (lane == 0) red[wave] = v;
    __syncthreads();
    if (threadIdx.x == 0) bsum[blockIdx.x] = red[0] + red[1] + red[2] + red[3];
}

// B: single-block exclusive scan of nb (<=256) block sums, in place
__global__ __launch_bounds__(256) void scan_boff(int* __restrict__ bsum, int nb) {
    __shared__ int buf[256];
    int tid = threadIdx.x;
    int v = (tid < nb) ? bsum[tid] : 0;
    buf[tid] = v;
    __syncthreads();
    #pragma unroll
    for (int off = 1; off < 256; off <<= 1) {
        int t = (tid >= off) ? buf[tid - off] : 0;
        __syncthreads();
        buf[tid] += t;
        __syncthreads();
    }
    if (tid < nb) bsum[tid] = buf[tid] - v;  // exclusive
}

// C: per-block exclusive scan + block offset -> rs, cur
__global__ __launch_bounds__(256) void scan_final(const int* __restrict__ cnt,
                                                  const int* __restrict__ boff,
                                                  int* __restrict__ rs,
                                                  int* __restrict__ cur, int n) {
    __shared__ int buf[256];
    int tid = threadIdx.x;
    int i = blockIdx.x * 256 + tid;
    int v = (i < n) ? cnt[i] : 0;
    buf[tid] = v;
    __syncthreads();
    #pragma unroll
    for (int off = 1; off < 256; off <<= 1) {
        int t = (tid >= off) ? buf[tid - off] : 0;
        __syncthreads();
        buf[tid] += t;
        __syncthreads();
    }
    int ex = buf[tid] - v + boff[blockIdx.x];
    if (i < n) { rs[i] = ex; cur[i] = ex; }
    if (i == n - 1) rs[n] = ex + v;
}

// Scatter edges into dst-sorted order
__global__ __launch_bounds__(256) void scatter_kernel(const int* __restrict__ src,
                                                      const int* __restrict__ dst,
                                                      const float* __restrict__ w,
                                                      int* __restrict__ cur,
                                                      int* __restrict__ ssrc,
                                                      float* __restrict__ sw, int E) {
    int i = blockIdx.x * 256 + threadIdx.x;
    if (i >= E) return;
    int p = atomicAdd(&cur[dst[i]], 1);
    ssrc[p] = src[i];
    sw[p] = w[i];
}

// ---------------------------------------------------------------------------
// C[M,128] = A[M,K] @ B[K,128]; 64x128 tile per block, 256 threads, BK=16.
// A tile stored TRANSPOSED in LDS (a_s[k][row], +4 pad keeps 16B alignment
// and spreads staging-write banks) so inner loop reads A via ds_read_b128.
__global__ __launch_bounds__(256) void gemm_n128(const float* __restrict__ A,
                                                 const float* __restrict__ B,
                                                 float* __restrict__ C, int M, int K) {
    __shared__ float a_s[16][68];
    __shared__ float b_s[16][128];
    int tid = threadIdx.x;
    int row0 = blockIdx.x * 64;
    int tx = tid & 31;   // col group: cols tx*4..tx*4+3
    int ty = tid >> 5;   // row group: rows ty*8..ty*8+7
    float acc[8][4] = {};
    for (int k0 = 0; k0 < K; k0 += 16) {
        // A tile: 64 rows x 16 k, one float4 per thread, transposed into LDS
        {
            int r = tid >> 2;
            int kc = (tid & 3) << 2;
            int gr = row0 + r;
            float4 v = make_float4(0.f, 0.f, 0.f, 0.f);
            if (gr < M) v = *(const float4*)&A[(size_t)gr * K + k0 + kc];
            a_s[kc + 0][r] = v.x;
            a_s[kc + 1][r] = v.y;
            a_s[kc + 2][r] = v.z;
            a_s[kc + 3][r] = v.w;
        }
        // B tile: 16 x 128 = 512 float4, two per thread
        #pragma unroll
        for (int i = 0; i < 2; ++i) {
            int f4 = tid * 2 + i;
            int kr = f4 >> 5;
            int c = (f4 & 31) << 2;
            *(float4*)&b_s[kr][c] = *(const float4*)&B[(size_t)(k0 + kr) * 128 + c];
        }
        __syncthreads();
        #pragma unroll
        for (int k = 0; k < 16; ++k) {
            float4 b4 = *(const float4*)&b_s[k][tx * 4];
            float4 a0 = *(const float4*)&a_s[k][ty * 8];
            float4 a1 = *(const float4*)&a_s[k][ty * 8 + 4];
            float av[8] = {a0.x, a0.y, a0.z, a0.w, a1.x, a1.y, a1.z, a1.w};
            #pragma unroll
            for (int i = 0; i < 8; ++i) {
                acc[i][0] += av[i] * b4.x;
                acc[i][1] += av[i] * b4.y;
                acc[i][2] += av[i] * b4.z;
                acc[i][3] += av[i] * b4.w;
            }
        }
        __syncthreads();
    }
    for (int i = 0; i < 8; ++i) {
        int gr = row0 + ty * 8 + i;
        if (gr < M)
            *(float4*)&C[(size_t)gr * 128 + tx * 4] =
                make_float4(acc[i][0], acc[i][1], acc[i][2], acc[i][3]);
    }
}

// C[M,40] = A[M,128] @ W[128,40]  (W is 20KB -> L1-resident)
__global__ __launch_bounds__(256) void gemm_n40(const float* __restrict__ A,
                                                const float* __restrict__ W,
                                                float* __restrict__ C, int M) {
    int idx = blockIdx.x * 256 + threadIdx.x;
    int row = idx / 40;
    int col = idx - row * 40;
    if (row >= M) return;
    const float* a = A + (size_t)row * 128;
    float acc = 0.f;
    #pragma unroll 8
    for (int k = 0; k < 128; ++k) acc += a[k] * W[k * 40 + col];
    C[(size_t)row * 40 + col] = acc;
}

// ---------------------------------------------------------------------------
// out[n,128] = segment_sum over CSR of sup[src]*w + bias, optional relu.
// One wave per node; lane covers 2 features (float2).
__global__ __launch_bounds__(256) void spmm128(const float2* __restrict__ sup,
                                               const int* __restrict__ rs,
                                               const int* __restrict__ ssrc,
                                               const float* __restrict__ sw,
                                               const float* __restrict__ bias,
                                               float2* __restrict__ out, int n,
                                               int do_relu) {
    int wid = blockIdx.x * 4 + (threadIdx.x >> 6);
    int lane = threadIdx.x & 63;
    if (wid >= n) return;
    int k = rs[wid], e = rs[wid + 1];
    float2 acc = make_float2(0.f, 0.f);
    for (; k < e; ++k) {
        int s = ssrc[k];
        float w = sw[k];
        float2 v = sup[(size_t)s * 64 + lane];
        acc.x += v.x * w;
        acc.y += v.y * w;
    }
    float ox = acc.x + bias[lane * 2];
    float oy = acc.y + bias[lane * 2 + 1];
    if (do_relu) { ox = fmaxf(ox, 0.f); oy = fmaxf(oy, 0.f); }
    out[(size_t)wid * 64 + lane] = make_float2(ox, oy);
}

// Layer 3: F=40 segment-sum + bias + log_softmax fused, writes d_out
__global__ __launch_bounds__(256) void spmm40_lsm(const float* __restrict__ sup,
                                                  const int* __restrict__ rs,
                                                  const int* __restrict__ ssrc,
                                                  const float* __restrict__ sw,
                                                  const float* __restrict__ bias,
                                                  float* __restrict__ out, int n) {
    int wid = blockIdx.x * 4 + (threadIdx.x >> 6);
    int lane = threadIdx.x & 63;
    if (wid >= n) return;
    float v = -INFINITY;
    if (lane < 40) {
        int k = rs[wid], e = rs[wid + 1];
        float acc = 0.f;
        for (; k < e; ++k) acc += sup[(size_t)ssrc[k] * 40 + lane] * sw[k];
        v = acc + bias[lane];
    }
    float m = v;
    #pragma unroll
    for (int off = 32; off; off >>= 1) m = fmaxf(m, __shfl_xor(m, off, 64));
    float ex = (lane < 40) ? expf(v - m) : 0.f;
    float s = ex;
    #pragma unroll
    for (int off = 32; off; off >>= 1) s += __shfl_xor(s, off, 64);
    float ls = logf(s);
    if (lane < 40) out[(size_t)wid * 40 + lane] = v - m - ls;
}

// ---------------------------------------------------------------------------
extern "C" void kernel_launch(void* const* d_in, const int* in_sizes, int n_in,
                              void* d_out, int out_size, void* d_ws, size_t ws_size,
                              hipStream_t stream) {
    const float* x   = (const float*)d_in[0];
    const float* ew  = (const float*)d_in[1];
    const float* W1  = (const float*)d_in[2];
    const float* b1  = (const float*)d_in[3];
    const float* W2  = (const float*)d_in[4];
    const float* b2  = (const float*)d_in[5];
    const float* W3  = (const float*)d_in[6];
    const float* b3  = (const float*)d_in[7];
    const int* esrc  = (const int*)d_in[8];
    const int* edst  = (const int*)d_in[9];
    float* out = (float*)d_out;

    char* ws = (char*)d_ws;
    size_t off = 0;
    auto alloc = [&](size_t bytes) {
        size_t cur = off;
        off += (bytes + 255) & ~(size_t)255;
        return cur;
    };
    int* cnt      = (int*)(ws + alloc((N_NODES + 1) * sizeof(int)));
    int* rs       = (int*)(ws + alloc((N_NODES + 1) * sizeof(int)));
    int* cur      = (int*)(ws + alloc(N_NODES * sizeof(int)));
    int* bsum     = (int*)(ws + alloc(256 * sizeof(int)));
    int* ssrc     = (int*)(ws + alloc(N_EDGES * sizeof(int)));
    float* sw     = (float*)(ws + alloc(N_EDGES * sizeof(float)));
    float* bufA   = (float*)(ws + alloc((size_t)N_NODES * 128 * sizeof(float)));
    float* bufB   = (float*)(ws + alloc((size_t)N_NODES * 128 * sizeof(float)));

    int scan_blocks = (N_NODES + 255) / 256;  // 196

    // --- CSR build ---
    hipMemsetAsync(cnt, 0, (N_NODES + 1) * sizeof(int), stream);
    hist_kernel<<<(N_EDGES + 255) / 256, 256, 0, stream>>>(edst, cnt, N_EDGES);
    scan_bsum<<<scan_blocks, 256, 0, stream>>>(cnt, bsum, N_NODES);
    scan_boff<<<1, 256, 0, stream>>>(bsum, scan_blocks);
    scan_final<<<scan_blocks, 256, 0, stream>>>(cnt, bsum, rs, cur, N_NODES);
    scatter_kernel<<<(N_EDGES + 255) / 256, 256, 0, stream>>>(esrc, edst, ew, cur,
                                                              ssrc, sw, N_EDGES);

    int gemm_blocks = (N_NODES + 63) / 64;           // 782
    int spmm_blocks = (N_NODES + 3) / 4;             // 12500

    // --- layer 1 ---
    gemm_n128<<<gemm_blocks, 256, 0, stream>>>(x, W1, bufA, N_NODES, NFEAT);
    spmm128<<<spmm_blocks, 256, 0, stream>>>((const float2*)bufA, rs, ssrc, sw, b1,
                                             (float2*)bufB, N_NODES, 1);
    // --- layer 2 ---
    gemm_n128<<<gemm_blocks, 256, 0, stream>>>(bufB, W2, bufA, N_NODES, NHID);
    spmm128<<<spmm_blocks, 256, 0, stream>>>((const float2*)bufA, rs, ssrc, sw, b2,
                                             (float2*)bufB, N_NODES, 1);
    // --- layer 3 ---
    gemm_n40<<<((size_t)N_NODES * 40 + 255) / 256, 256, 0, stream>>>(bufB, W3, bufA,
                                                                     N_NODES);
    spmm40_lsm<<<spmm_blocks, 256, 0, stream>>>(bufA, rs, ssrc, sw, b3, out, N_NODES);
}

// Round 3
// 406.676 us; speedup vs baseline: 1.5352x; 1.2759x over previous
//
#include <hip/hip_runtime.h>
#include <hip/hip_bf16.h>
#include <math.h>

#define N_NODES 50000
#define N_EDGES 600000
#define NFEAT   256
#define NHID    128
#define NCLASS  40

typedef __attribute__((ext_vector_type(8))) short bf16x8;
typedef __attribute__((ext_vector_type(4))) float f32x4;

__device__ inline ushort f2bf(float f) {   // RNE, finite inputs
    uint u = __float_as_uint(f);
    uint r = (u + 0x7fffu + ((u >> 16) & 1u)) >> 16;
    return (ushort)r;
}

// ---------------------------------------------------------------------------
// CSR build
__global__ __launch_bounds__(256) void hist_kernel(const int* __restrict__ dst,
                                                   int* __restrict__ cnt, int E) {
    int i = blockIdx.x * 256 + threadIdx.x;
    if (i < E) atomicAdd(&cnt[dst[i]], 1);
}

__global__ __launch_bounds__(256) void scan_bsum(const int* __restrict__ cnt,
                                                 int* __restrict__ bsum, int n) {
    __shared__ int red[4];
    int i = blockIdx.x * 256 + threadIdx.x;
    int v = (i < n) ? cnt[i] : 0;
    #pragma unroll
    for (int off = 32; off; off >>= 1) v += __shfl_down(v, off, 64);
    int wave = threadIdx.x >> 6, lane = threadIdx.x & 63;
    if (lane == 0) red[wave] = v;
    __syncthreads();
    if (threadIdx.x == 0) bsum[blockIdx.x] = red[0] + red[1] + red[2] + red[3];
}

__global__ __launch_bounds__(256) void scan_boff(int* __restrict__ bsum, int nb) {
    __shared__ int buf[256];
    int tid = threadIdx.x;
    int v = (tid < nb) ? bsum[tid] : 0;
    buf[tid] = v;
    __syncthreads();
    #pragma unroll
    for (int off = 1; off < 256; off <<= 1) {
        int t = (tid >= off) ? buf[tid - off] : 0;
        __syncthreads();
        buf[tid] += t;
        __syncthreads();
    }
    if (tid < nb) bsum[tid] = buf[tid] - v;
}

__global__ __launch_bounds__(256) void scan_final(const int* __restrict__ cnt,
                                                  const int* __restrict__ boff,
                                                  int* __restrict__ rs,
                                                  int* __restrict__ cur, int n) {
    __shared__ int buf[256];
    int tid = threadIdx.x;
    int i = blockIdx.x * 256 + tid;
    int v = (i < n) ? cnt[i] : 0;
    buf[tid] = v;
    __syncthreads();
    #pragma unroll
    for (int off = 1; off < 256; off <<= 1) {
        int t = (tid >= off) ? buf[tid - off] : 0;
        __syncthreads();
        buf[tid] += t;
        __syncthreads();
    }
    int ex = buf[tid] - v + boff[blockIdx.x];
    if (i < n) { rs[i] = ex; cur[i] = ex; }
    if (i == n - 1) rs[n] = ex + v;
}

__global__ __launch_bounds__(256) void scatter_kernel(const int* __restrict__ src,
                                                      const int* __restrict__ dst,
                                                      const float* __restrict__ w,
                                                      int* __restrict__ cur,
                                                      int* __restrict__ ssrc,
                                                      float* __restrict__ sw, int E) {
    int i = blockIdx.x * 256 + threadIdx.x;
    if (i >= E) return;
    int p = atomicAdd(&cur[dst[i]], 1);
    ssrc[p] = src[i];
    sw[p] = w[i];
}

// ---------------------------------------------------------------------------
// Converters
// fp32 -> bf16, 4 elems/thread (n must be multiple of 4)
__global__ __launch_bounds__(256) void cvt_bf16_vec(const float* __restrict__ in,
                                                    ushort* __restrict__ out, int n4) {
    int i = blockIdx.x * 256 + threadIdx.x;
    if (i >= n4) return;
    float4 v = *(const float4*)(in + (size_t)i * 4);
    ushort4 o;
    o.x = f2bf(v.x); o.y = f2bf(v.y); o.z = f2bf(v.z); o.w = f2bf(v.w);
    *(ushort4*)(out + (size_t)i * 4) = o;
}

// W [K x N] fp32 -> BT [Wr x K] bf16 (rows >= N zero-padded)
__global__ __launch_bounds__(256) void cvt_wT(const float* __restrict__ W,
                                              ushort* __restrict__ BT,
                                              int K, int N, int Wr) {
    int idx = blockIdx.x * 256 + threadIdx.x;
    if (idx >= Wr * K) return;
    int nr = idx / K, k = idx - nr * K;
    float v = (nr < N) ? W[(size_t)k * N + nr] : 0.f;
    BT[idx] = f2bf(v);
}

// ---------------------------------------------------------------------------
// bf16 MFMA GEMM: C[M x Nout] = A[M x K] @ BT[.. x K]^T
// Block: 64 rows x (4 waves * NT * 16) cols. 16x16x32 MFMA, fp32 accum.
// LDS row stride 40 ushorts (80 B) -> 16B-aligned b128 frags, banks spread.
template<int NT, bool OUTBF>
__global__ __launch_bounds__(256) void gemm_mfma(const ushort* __restrict__ A,
                                                 const ushort* __restrict__ BT,
                                                 int M, int K, int Nout,
                                                 void* __restrict__ Cout) {
    __shared__ ushort a_s[64 * 40];
    __shared__ ushort b_s[64 * NT * 40];
    int tid = threadIdx.x;
    int row0 = blockIdx.x * 64;
    int wave = tid >> 6, lane = tid & 63;
    int lr = lane & 15, lk = (lane >> 4) * 8;
    f32x4 acc[4][NT];
    #pragma unroll
    for (int mt = 0; mt < 4; ++mt)
        #pragma unroll
        for (int nt = 0; nt < NT; ++nt) acc[mt][nt] = (f32x4){0.f, 0.f, 0.f, 0.f};

    for (int k0 = 0; k0 < K; k0 += 32) {
        {   // A tile: 64 rows x 32 k, one 16B chunk/thread
            int r = tid >> 2, c8 = (tid & 3) * 8;
            int gr = row0 + r; if (gr >= M) gr = M - 1;  // clamp, store-guarded
            float4 v = *(const float4*)(A + (size_t)gr * K + k0 + c8);
            *(float4*)(a_s + r * 40 + c8) = v;
        }
        #pragma unroll
        for (int i = 0; i < NT; ++i) {  // BT tile: 64*NT rows x 32 k
            int idx = tid * NT + i;
            int r = idx >> 2, c8 = (idx & 3) * 8;
            float4 v = *(const float4*)(BT + (size_t)r * K + k0 + c8);
            *(float4*)(b_s + r * 40 + c8) = v;
        }
        __syncthreads();
        bf16x8 bfr[NT];
        #pragma unroll
        for (int nt = 0; nt < NT; ++nt)
            bfr[nt] = *(const bf16x8*)(b_s + ((wave * NT + nt) * 16 + lr) * 40 + lk);
        #pragma unroll
        for (int mt = 0; mt < 4; ++mt) {
            bf16x8 afr = *(const bf16x8*)(a_s + (mt * 16 + lr) * 40 + lk);
            #pragma unroll
            for (int nt = 0; nt < NT; ++nt)
                acc[mt][nt] = __builtin_amdgcn_mfma_f32_16x16x32_bf16(
                    afr, bfr[nt], acc[mt][nt], 0, 0, 0);
        }
        __syncthreads();
    }
    // C/D layout: col = lane&15, row = (lane>>4)*4 + i
    int col0 = wave * NT * 16;
    #pragma unroll
    for (int mt = 0; mt < 4; ++mt) {
        int gr0 = row0 + mt * 16 + (lane >> 4) * 4;
        #pragma unroll
        for (int nt = 0; nt < NT; ++nt) {
            int gc = col0 + nt * 16 + lr;
            #pragma unroll
            for (int i = 0; i < 4; ++i) {
                int gr = gr0 + i;
                if (gr < M && gc < Nout) {
                    if (OUTBF)
                        ((ushort*)Cout)[(size_t)gr * Nout + gc] = f2bf(acc[mt][nt][i]);
                    else
                        ((float*)Cout)[(size_t)gr * Nout + gc] = acc[mt][nt][i];
                }
            }
        }
    }
}

// ---------------------------------------------------------------------------
// SpMM over bf16 support (uint = 2 bf16 features/lane), fp32 accum,
// bias+ReLU fused, bf16 output. One wave per node.
__global__ __launch_bounds__(256) void spmm128b(const uint* __restrict__ sup,
                                                const int* __restrict__ rs,
                                                const int* __restrict__ ssrc,
                                                const float* __restrict__ sw,
                                                const float* __restrict__ bias,
                                                uint* __restrict__ outb, int n) {
    int wid = blockIdx.x * 4 + (threadIdx.x >> 6);
    int lane = threadIdx.x & 63;
    if (wid >= n) return;
    int k = rs[wid], e = rs[wid + 1];
    float ax = 0.f, ay = 0.f;
    for (; k < e; ++k) {
        int s = ssrc[k];
        float w = sw[k];
        uint p = sup[(size_t)s * 64 + lane];
        ax += __uint_as_float(p << 16) * w;
        ay += __uint_as_float(p & 0xffff0000u) * w;
    }
    ax = fmaxf(ax + bias[lane * 2], 0.f);
    ay = fmaxf(ay + bias[lane * 2 + 1], 0.f);
    outb[(size_t)wid * 64 + lane] = ((uint)f2bf(ay) << 16) | (uint)f2bf(ax);
}

// Layer 3: fp32 F=40 segment-sum + bias + log_softmax fused -> d_out
__global__ __launch_bounds__(256) void spmm40_lsm(const float* __restrict__ sup,
                                                  const int* __restrict__ rs,
                                                  const int* __restrict__ ssrc,
                                                  const float* __restrict__ sw,
                                                  const float* __restrict__ bias,
                                                  float* __restrict__ out, int n) {
    int wid = blockIdx.x * 4 + (threadIdx.x >> 6);
    int lane = threadIdx.x & 63;
    if (wid >= n) return;
    float v = -INFINITY;
    if (lane < 40) {
        int k = rs[wid], e = rs[wid + 1];
        float acc = 0.f;
        for (; k < e; ++k) acc += sup[(size_t)ssrc[k] * 40 + lane] * sw[k];
        v = acc + bias[lane];
    }
    float m = v;
    #pragma unroll
    for (int off = 32; off; off >>= 1) m = fmaxf(m, __shfl_xor(m, off, 64));
    float ex = (lane < 40) ? expf(v - m) : 0.f;
    float s = ex;
    #pragma unroll
    for (int off = 32; off; off >>= 1) s += __shfl_xor(s, off, 64);
    float ls = logf(s);
    if (lane < 40) out[(size_t)wid * 40 + lane] = v - m - ls;
}

// ---------------------------------------------------------------------------
extern "C" void kernel_launch(void* const* d_in, const int* in_sizes, int n_in,
                              void* d_out, int out_size, void* d_ws, size_t ws_size,
                              hipStream_t stream) {
    const float* x   = (const float*)d_in[0];
    const float* ew  = (const float*)d_in[1];
    const float* W1  = (const float*)d_in[2];
    const float* b1  = (const float*)d_in[3];
    const float* W2  = (const float*)d_in[4];
    const float* b2  = (const float*)d_in[5];
    const float* W3  = (const float*)d_in[6];
    const float* b3  = (const float*)d_in[7];
    const int* esrc  = (const int*)d_in[8];
    const int* edst  = (const int*)d_in[9];
    float* out = (float*)d_out;

    char* ws = (char*)d_ws;
    size_t off = 0;
    auto alloc = [&](size_t bytes) {
        size_t cur = off;
        off += (bytes + 255) & ~(size_t)255;
        return cur;
    };
    int* cnt     = (int*)(ws + alloc((N_NODES + 1) * sizeof(int)));
    int* rs      = (int*)(ws + alloc((N_NODES + 1) * sizeof(int)));
    int* cur     = (int*)(ws + alloc(N_NODES * sizeof(int)));   // reused for BTs
    int* bsum    = (int*)(ws + alloc(256 * sizeof(int)));
    int* ssrc    = (int*)(ws + alloc(N_EDGES * sizeof(int)));
    float* sw    = (float*)(ws + alloc(N_EDGES * sizeof(float)));
    char* Xreg   = ws + alloc((size_t)N_NODES * 256 * 2);       // 25.6 MB
    char* Sreg   = ws + alloc((size_t)N_NODES * 128 * 2);       // 12.8 MB
    char* Hreg   = ws + alloc((size_t)N_NODES * 128 * 2);       // 12.8 MB

    // cur (200 KB) is dead after scatter_kernel; BTs (112 KB) live there.
    ushort* BT1 = (ushort*)cur;                    // 128 x 256  (64 KB)
    ushort* BT2 = (ushort*)((char*)cur + 65536);   // 128 x 128  (32 KB)
    ushort* BT3 = (ushort*)((char*)cur + 98304);   // 64  x 128  (16 KB, rows>=40 zero)

    ushort* xb   = (ushort*)Xreg;                  // x as bf16 [N x 256]
    ushort* supA = (ushort*)Sreg;                  // gemm1 out
    ushort* hA   = (ushort*)Hreg;                  // spmm1 out
    ushort* supB = (ushort*)Xreg;                  // gemm2 out (xb dead)
    ushort* hB   = (ushort*)Sreg;                  // spmm2 out (supA dead)
    float*  sup3 = (float*)(Xreg + 12800000);      // gemm3 out fp32 [N x 40]

    // --- CSR build (cur live here) ---
    hipMemsetAsync(cnt, 0, (N_NODES + 1) * sizeof(int), stream);
    hist_kernel<<<(N_EDGES + 255) / 256, 256, 0, stream>>>(edst, cnt, N_EDGES);
    int scan_blocks = (N_NODES + 255) / 256;  // 196
    scan_bsum<<<scan_blocks, 256, 0, stream>>>(cnt, bsum, N_NODES);
    scan_boff<<<1, 256, 0, stream>>>(bsum, scan_blocks);
    scan_final<<<scan_blocks, 256, 0, stream>>>(cnt, bsum, rs, cur, N_NODES);
    scatter_kernel<<<(N_EDGES + 255) / 256, 256, 0, stream>>>(esrc, edst, ew, cur,
                                                              ssrc, sw, N_EDGES);

    // --- conversions (cur now dead -> BTs) ---
    cvt_bf16_vec<<<(N_NODES * 256 / 4 + 255) / 256, 256, 0, stream>>>(x, xb,
                                                                      N_NODES * 64);
    cvt_wT<<<(128 * 256 + 255) / 256, 256, 0, stream>>>(W1, BT1, 256, 128, 128);
    cvt_wT<<<(128 * 128 + 255) / 256, 256, 0, stream>>>(W2, BT2, 128, 128, 128);
    cvt_wT<<<(64 * 128 + 255) / 256, 256, 0, stream>>>(W3, BT3, 128, 40, 64);

    int gemm_blocks = (N_NODES + 63) / 64;   // 782
    int spmm_blocks = (N_NODES + 3) / 4;     // 12500

    // --- layer 1 ---
    gemm_mfma<2, true><<<gemm_blocks, 256, 0, stream>>>(xb, BT1, N_NODES, 256, 128,
                                                        supA);
    spmm128b<<<spmm_blocks, 256, 0, stream>>>((const uint*)supA, rs, ssrc, sw, b1,
                                              (uint*)hA, N_NODES);
    // --- layer 2 ---
    gemm_mfma<2, true><<<gemm_blocks, 256, 0, stream>>>(hA, BT2, N_NODES, 128, 128,
                                                        supB);
    spmm128b<<<spmm_blocks, 256, 0, stream>>>((const uint*)supB, rs, ssrc, sw, b2,
                                              (uint*)hB, N_NODES);
    // --- layer 3 ---
    gemm_mfma<1, false><<<gemm_blocks, 256, 0, stream>>>(hB, BT3, N_NODES, 128, 40,
                                                         sup3);
    spmm40_lsm<<<spmm_blocks, 256, 0, stream>>>(sup3, rs, ssrc, sw, b3, out, N_NODES);
}

// Round 4
// 304.644 us; speedup vs baseline: 2.0493x; 1.3349x over previous
//
#include <hip/hip_runtime.h>
#include <hip/hip_bf16.h>
#include <math.h>

#define N_NODES 50000
#define N_EDGES 600000
#define NFEAT   256
#define NHID    128
#define NCLASS  40

typedef __attribute__((ext_vector_type(8))) short bf16x8;
typedef __attribute__((ext_vector_type(4))) float f32x4;

__device__ inline ushort f2bf(float f) {   // RNE, finite inputs
    uint u = __float_as_uint(f);
    uint r = (u + 0x7fffu + ((u >> 16) & 1u)) >> 16;
    return (ushort)r;
}

// ---------------------------------------------------------------------------
// CSR build
__global__ __launch_bounds__(256) void hist_kernel(const int* __restrict__ dst,
                                                   int* __restrict__ cnt, int E) {
    int i = blockIdx.x * 256 + threadIdx.x;
    if (i < E) atomicAdd(&cnt[dst[i]], 1);
}

__global__ __launch_bounds__(256) void scan_bsum(const int* __restrict__ cnt,
                                                 int* __restrict__ bsum, int n) {
    __shared__ int red[4];
    int i = blockIdx.x * 256 + threadIdx.x;
    int v = (i < n) ? cnt[i] : 0;
    #pragma unroll
    for (int off = 32; off; off >>= 1) v += __shfl_down(v, off, 64);
    int wave = threadIdx.x >> 6, lane = threadIdx.x & 63;
    if (lane == 0) red[wave] = v;
    __syncthreads();
    if (threadIdx.x == 0) bsum[blockIdx.x] = red[0] + red[1] + red[2] + red[3];
}

__global__ __launch_bounds__(256) void scan_boff(int* __restrict__ bsum, int nb) {
    __shared__ int buf[256];
    int tid = threadIdx.x;
    int v = (tid < nb) ? bsum[tid] : 0;
    buf[tid] = v;
    __syncthreads();
    #pragma unroll
    for (int off = 1; off < 256; off <<= 1) {
        int t = (tid >= off) ? buf[tid - off] : 0;
        __syncthreads();
        buf[tid] += t;
        __syncthreads();
    }
    if (tid < nb) bsum[tid] = buf[tid] - v;
}

__global__ __launch_bounds__(256) void scan_final(const int* __restrict__ cnt,
                                                  const int* __restrict__ boff,
                                                  int* __restrict__ rs,
                                                  int* __restrict__ cur, int n) {
    __shared__ int buf[256];
    int tid = threadIdx.x;
    int i = blockIdx.x * 256 + tid;
    int v = (i < n) ? cnt[i] : 0;
    buf[tid] = v;
    __syncthreads();
    #pragma unroll
    for (int off = 1; off < 256; off <<= 1) {
        int t = (tid >= off) ? buf[tid - off] : 0;
        __syncthreads();
        buf[tid] += t;
        __syncthreads();
    }
    int ex = buf[tid] - v + boff[blockIdx.x];
    if (i < n) { rs[i] = ex; cur[i] = ex; }
    if (i == n - 1) rs[n] = ex + v;
}

__global__ __launch_bounds__(256) void scatter_kernel(const int* __restrict__ src,
                                                      const int* __restrict__ dst,
                                                      const float* __restrict__ w,
                                                      int* __restrict__ cur,
                                                      int* __restrict__ ssrc,
                                                      float* __restrict__ sw, int E) {
    int i = blockIdx.x * 256 + threadIdx.x;
    if (i >= E) return;
    int p = atomicAdd(&cur[dst[i]], 1);
    ssrc[p] = src[i];
    sw[p] = w[i];
}

// ---------------------------------------------------------------------------
// Converters
__global__ __launch_bounds__(256) void cvt_bf16_vec(const float* __restrict__ in,
                                                    ushort* __restrict__ out, int n4) {
    int i = blockIdx.x * 256 + threadIdx.x;
    if (i >= n4) return;
    float4 v = *(const float4*)(in + (size_t)i * 4);
    ushort4 o;
    o.x = f2bf(v.x); o.y = f2bf(v.y); o.z = f2bf(v.z); o.w = f2bf(v.w);
    *(ushort4*)(out + (size_t)i * 4) = o;
}

// W [K x N] fp32 -> BT [Wr x K] bf16 (rows >= N zero-padded)
__global__ __launch_bounds__(256) void cvt_wT(const float* __restrict__ W,
                                              ushort* __restrict__ BT,
                                              int K, int N, int Wr) {
    int idx = blockIdx.x * 256 + threadIdx.x;
    if (idx >= Wr * K) return;
    int nr = idx / K, k = idx - nr * K;
    float v = (nr < N) ? W[(size_t)k * N + nr] : 0.f;
    BT[idx] = f2bf(v);
}

// ---------------------------------------------------------------------------
// bf16 MFMA GEMM: C[M x Nout] = A[M x K] @ BT[.. x K]^T
template<int NT, bool OUTBF>
__global__ __launch_bounds__(256) void gemm_mfma(const ushort* __restrict__ A,
                                                 const ushort* __restrict__ BT,
                                                 int M, int K, int Nout,
                                                 void* __restrict__ Cout) {
    __shared__ ushort a_s[64 * 40];
    __shared__ ushort b_s[64 * NT * 40];
    int tid = threadIdx.x;
    int row0 = blockIdx.x * 64;
    int wave = tid >> 6, lane = tid & 63;
    int lr = lane & 15, lk = (lane >> 4) * 8;
    f32x4 acc[4][NT];
    #pragma unroll
    for (int mt = 0; mt < 4; ++mt)
        #pragma unroll
        for (int nt = 0; nt < NT; ++nt) acc[mt][nt] = (f32x4){0.f, 0.f, 0.f, 0.f};

    for (int k0 = 0; k0 < K; k0 += 32) {
        {   // A tile: 64 rows x 32 k, one 16B chunk/thread
            int r = tid >> 2, c8 = (tid & 3) * 8;
            int gr = row0 + r; if (gr >= M) gr = M - 1;  // clamp, store-guarded
            float4 v = *(const float4*)(A + (size_t)gr * K + k0 + c8);
            *(float4*)(a_s + r * 40 + c8) = v;
        }
        #pragma unroll
        for (int i = 0; i < NT; ++i) {  // BT tile: 64*NT rows x 32 k
            int idx = tid * NT + i;
            int r = idx >> 2, c8 = (idx & 3) * 8;
            float4 v = *(const float4*)(BT + (size_t)r * K + k0 + c8);
            *(float4*)(b_s + r * 40 + c8) = v;
        }
        __syncthreads();
        bf16x8 bfr[NT];
        #pragma unroll
        for (int nt = 0; nt < NT; ++nt)
            bfr[nt] = *(const bf16x8*)(b_s + ((wave * NT + nt) * 16 + lr) * 40 + lk);
        #pragma unroll
        for (int mt = 0; mt < 4; ++mt) {
            bf16x8 afr = *(const bf16x8*)(a_s + (mt * 16 + lr) * 40 + lk);
            #pragma unroll
            for (int nt = 0; nt < NT; ++nt)
                acc[mt][nt] = __builtin_amdgcn_mfma_f32_16x16x32_bf16(
                    afr, bfr[nt], acc[mt][nt], 0, 0, 0);
        }
        __syncthreads();
    }
    // C/D layout: col = lane&15, row = (lane>>4)*4 + i
    int col0 = wave * NT * 16;
    #pragma unroll
    for (int mt = 0; mt < 4; ++mt) {
        int gr0 = row0 + mt * 16 + (lane >> 4) * 4;
        #pragma unroll
        for (int nt = 0; nt < NT; ++nt) {
            int gc = col0 + nt * 16 + lr;
            #pragma unroll
            for (int i = 0; i < 4; ++i) {
                int gr = gr0 + i;
                if (gr < M && gc < Nout) {
                    if (OUTBF)
                        ((ushort*)Cout)[(size_t)gr * Nout + gc] = f2bf(acc[mt][nt][i]);
                    else
                        ((float*)Cout)[(size_t)gr * Nout + gc] = acc[mt][nt][i];
                }
            }
        }
    }
}

// ---------------------------------------------------------------------------
// SpMM over bf16 support, 8-edge batched for MLP. One wave per node.
// Predicated full-width groups: dup last edge with weight 0.
__global__ __launch_bounds__(256) void spmm128b(const uint* __restrict__ sup,
                                                const int* __restrict__ rs,
                                                const int* __restrict__ ssrc,
                                                const float* __restrict__ sw,
                                                const float* __restrict__ bias,
                                                uint* __restrict__ outb, int n) {
    int wid = blockIdx.x * 4 + (threadIdx.x >> 6);
    int lane = threadIdx.x & 63;
    if (wid >= n) return;
    int k = rs[wid], e = rs[wid + 1];
    float ax = 0.f, ay = 0.f;
    while (k < e) {
        int s[8]; float w[8];
        #pragma unroll
        for (int j = 0; j < 8; ++j) {
            int kk = k + j;
            int kc = (kk < e) ? kk : (e - 1);
            s[j] = ssrc[kc];
            w[j] = (kk < e) ? sw[kk] : 0.f;
        }
        uint p[8];
        #pragma unroll
        for (int j = 0; j < 8; ++j) p[j] = sup[(size_t)s[j] * 64 + lane];
        #pragma unroll
        for (int j = 0; j < 8; ++j) {
            ax += __uint_as_float(p[j] << 16) * w[j];
            ay += __uint_as_float(p[j] & 0xffff0000u) * w[j];
        }
        k += 8;
    }
    ax = fmaxf(ax + bias[lane * 2], 0.f);
    ay = fmaxf(ay + bias[lane * 2 + 1], 0.f);
    outb[(size_t)wid * 64 + lane] = ((uint)f2bf(ay) << 16) | (uint)f2bf(ax);
}

// Layer 3: fp32 F=40 segment-sum + bias + log_softmax fused -> d_out
__global__ __launch_bounds__(256) void spmm40_lsm(const float* __restrict__ sup,
                                                  const int* __restrict__ rs,
                                                  const int* __restrict__ ssrc,
                                                  const float* __restrict__ sw,
                                                  const float* __restrict__ bias,
                                                  float* __restrict__ out, int n) {
    int wid = blockIdx.x * 4 + (threadIdx.x >> 6);
    int lane = threadIdx.x & 63;
    if (wid >= n) return;
    int k = rs[wid], e = rs[wid + 1];
    float acc = 0.f;
    int lf = (lane < 40) ? lane : 39;  // inactive lanes read lane 39 (no OOB)
    while (k < e) {
        int s[8]; float w[8];
        #pragma unroll
        for (int j = 0; j < 8; ++j) {
            int kk = k + j;
            int kc = (kk < e) ? kk : (e - 1);
            s[j] = ssrc[kc];
            w[j] = (kk < e) ? sw[kk] : 0.f;
        }
        float p[8];
        #pragma unroll
        for (int j = 0; j < 8; ++j) p[j] = sup[(size_t)s[j] * 40 + lf];
        #pragma unroll
        for (int j = 0; j < 8; ++j) acc += p[j] * w[j];
        k += 8;
    }
    float v = (lane < 40) ? acc + bias[lane] : -INFINITY;
    float m = v;
    #pragma unroll
    for (int off = 32; off; off >>= 1) m = fmaxf(m, __shfl_xor(m, off, 64));
    float ex = (lane < 40) ? expf(v - m) : 0.f;
    float s = ex;
    #pragma unroll
    for (int off = 32; off; off >>= 1) s += __shfl_xor(s, off, 64);
    float ls = logf(s);
    if (lane < 40) out[(size_t)wid * 40 + lane] = v - m - ls;
}

// ---------------------------------------------------------------------------
extern "C" void kernel_launch(void* const* d_in, const int* in_sizes, int n_in,
                              void* d_out, int out_size, void* d_ws, size_t ws_size,
                              hipStream_t stream) {
    const float* x   = (const float*)d_in[0];
    const float* ew  = (const float*)d_in[1];
    const float* W1  = (const float*)d_in[2];
    const float* b1  = (const float*)d_in[3];
    const float* W2  = (const float*)d_in[4];
    const float* b2  = (const float*)d_in[5];
    const float* W3  = (const float*)d_in[6];
    const float* b3  = (const float*)d_in[7];
    const int* esrc  = (const int*)d_in[8];
    const int* edst  = (const int*)d_in[9];
    float* out = (float*)d_out;

    char* ws = (char*)d_ws;
    size_t off = 0;
    auto alloc = [&](size_t bytes) {
        size_t cur = off;
        off += (bytes + 255) & ~(size_t)255;
        return cur;
    };
    int* cnt     = (int*)(ws + alloc((N_NODES + 1) * sizeof(int)));
    int* rs      = (int*)(ws + alloc((N_NODES + 1) * sizeof(int)));
    int* cur     = (int*)(ws + alloc(N_NODES * sizeof(int)));   // reused for BTs
    int* bsum    = (int*)(ws + alloc(256 * sizeof(int)));
    int* ssrc    = (int*)(ws + alloc(N_EDGES * sizeof(int)));
    float* sw    = (float*)(ws + alloc(N_EDGES * sizeof(float)));
    char* Xreg   = ws + alloc((size_t)N_NODES * 256 * 2);       // 25.6 MB
    char* Sreg   = ws + alloc((size_t)N_NODES * 128 * 2);       // 12.8 MB
    char* Hreg   = ws + alloc((size_t)N_NODES * 128 * 2);       // 12.8 MB

    // cur (200 KB) is dead after scatter_kernel; BTs (112 KB) live there.
    ushort* BT1 = (ushort*)cur;                    // 128 x 256  (64 KB)
    ushort* BT2 = (ushort*)((char*)cur + 65536);   // 128 x 128  (32 KB)
    ushort* BT3 = (ushort*)((char*)cur + 98304);   // 64  x 128  (16 KB, rows>=40 zero)

    ushort* xb   = (ushort*)Xreg;                  // x as bf16 [N x 256]
    ushort* supA = (ushort*)Sreg;                  // gemm1 out
    ushort* hA   = (ushort*)Hreg;                  // spmm1 out
    ushort* supB = (ushort*)Xreg;                  // gemm2 out (xb dead)
    ushort* hB   = (ushort*)Sreg;                  // spmm2 out (supA dead)
    float*  sup3 = (float*)(Xreg + 12800000);      // gemm3 out fp32 [N x 40]

    // --- CSR build (cur live here) ---
    hipMemsetAsync(cnt, 0, (N_NODES + 1) * sizeof(int), stream);
    hist_kernel<<<(N_EDGES + 255) / 256, 256, 0, stream>>>(edst, cnt, N_EDGES);
    int scan_blocks = (N_NODES + 255) / 256;  // 196
    scan_bsum<<<scan_blocks, 256, 0, stream>>>(cnt, bsum, N_NODES);
    scan_boff<<<1, 256, 0, stream>>>(bsum, scan_blocks);
    scan_final<<<scan_blocks, 256, 0, stream>>>(cnt, bsum, rs, cur, N_NODES);
    scatter_kernel<<<(N_EDGES + 255) / 256, 256, 0, stream>>>(esrc, edst, ew, cur,
                                                              ssrc, sw, N_EDGES);

    // --- conversions (cur now dead -> BTs) ---
    cvt_bf16_vec<<<(N_NODES * 256 / 4 + 255) / 256, 256, 0, stream>>>(x, xb,
                                                                      N_NODES * 64);
    cvt_wT<<<(128 * 256 + 255) / 256, 256, 0, stream>>>(W1, BT1, 256, 128, 128);
    cvt_wT<<<(128 * 128 + 255) / 256, 256, 0, stream>>>(W2, BT2, 128, 128, 128);
    cvt_wT<<<(64 * 128 + 255) / 256, 256, 0, stream>>>(W3, BT3, 128, 40, 64);

    int gemm_blocks = (N_NODES + 63) / 64;   // 782
    int spmm_blocks = (N_NODES + 3) / 4;     // 12500

    // --- layer 1 ---
    gemm_mfma<2, true><<<gemm_blocks, 256, 0, stream>>>(xb, BT1, N_NODES, 256, 128,
                                                        supA);
    spmm128b<<<spmm_blocks, 256, 0, stream>>>((const uint*)supA, rs, ssrc, sw, b1,
                                              (uint*)hA, N_NODES);
    // --- layer 2 ---
    gemm_mfma<2, true><<<gemm_blocks, 256, 0, stream>>>(hA, BT2, N_NODES, 128, 128,
                                                        supB);
    spmm128b<<<spmm_blocks, 256, 0, stream>>>((const uint*)supB, rs, ssrc, sw, b2,
                                              (uint*)hB, N_NODES);
    // --- layer 3 ---
    gemm_mfma<1, false><<<gemm_blocks, 256, 0, stream>>>(hB, BT3, N_NODES, 128, 40,
                                                         sup3);
    spmm40_lsm<<<spmm_blocks, 256, 0, stream>>>(sup3, rs, ssrc, sw, b3, out, N_NODES);
}